// Round 1
// baseline (473.559 us; speedup 1.0000x reference)
//
#include <hip/hip_runtime.h>
#include <math.h>

#define CDIM 1024
#define RDIM 100
#define NBAGS 8192

__device__ __forceinline__ float dot4(float4 a, float4 b) {
    return a.x * b.x + a.y * b.y + a.z * b.z + a.w * b.w;
}

// Kernel 1: one wave per bag. Online softmax over the bag's rows with the
// full 1024-ch accumulator in registers (16 floats/lane). Reads X once.
__global__ __launch_bounds__(256) void bag_softmax_kernel(
    const float* __restrict__ X,
    const float* __restrict__ Constraints,
    const int* __restrict__ scope,
    const int* __restrict__ rel,
    float* __restrict__ bagbuf)
{
    const int wid  = threadIdx.x >> 6;
    const int lane = threadIdx.x & 63;
    const int bag  = blockIdx.x * 4 + wid;

    const int s = scope[2 * bag];
    const int e = scope[2 * bag + 1];
    const int r = rel[bag];

    const float4* conp = (const float4*)(Constraints + (size_t)r * CDIM);
    const float4 c0 = conp[lane];
    const float4 c1 = conp[lane + 64];
    const float4 c2 = conp[lane + 128];
    const float4 c3 = conp[lane + 192];

    float4 a0 = {0.f, 0.f, 0.f, 0.f};
    float4 a1 = {0.f, 0.f, 0.f, 0.f};
    float4 a2 = {0.f, 0.f, 0.f, 0.f};
    float4 a3 = {0.f, 0.f, 0.f, 0.f};
    float m = -INFINITY;
    float denom = 0.f;

    for (int row = s; row < e; ++row) {
        const float4* xr = (const float4*)(X + (size_t)row * CDIM);
        float4 x0 = xr[lane];
        float4 x1 = xr[lane + 64];
        float4 x2 = xr[lane + 128];
        float4 x3 = xr[lane + 192];

        float p = dot4(x0, c0) + dot4(x1, c1) + dot4(x2, c2) + dot4(x3, c3);
        #pragma unroll
        for (int off = 1; off < 64; off <<= 1)
            p += __shfl_xor(p, off);
        // p is now the full score, identical in all lanes.

        if (p <= m) {
            // no new max: just accumulate (common case after a few rows)
            float w = __expf(p - m);
            denom += w;
            a0.x += w * x0.x; a0.y += w * x0.y; a0.z += w * x0.z; a0.w += w * x0.w;
            a1.x += w * x1.x; a1.y += w * x1.y; a1.z += w * x1.z; a1.w += w * x1.w;
            a2.x += w * x2.x; a2.y += w * x2.y; a2.z += w * x2.z; a2.w += w * x2.w;
            a3.x += w * x3.x; a3.y += w * x3.y; a3.z += w * x3.z; a3.w += w * x3.w;
        } else {
            // new max: rescale running state. expf(-inf)=0 handles first row.
            float scale = __expf(m - p);
            m = p;
            denom = denom * scale + 1.0f;   // w = expf(p - p) = 1
            a0.x = a0.x * scale + x0.x; a0.y = a0.y * scale + x0.y;
            a0.z = a0.z * scale + x0.z; a0.w = a0.w * scale + x0.w;
            a1.x = a1.x * scale + x1.x; a1.y = a1.y * scale + x1.y;
            a1.z = a1.z * scale + x1.z; a1.w = a1.w * scale + x1.w;
            a2.x = a2.x * scale + x2.x; a2.y = a2.y * scale + x2.y;
            a2.z = a2.z * scale + x2.z; a2.w = a2.w * scale + x2.w;
            a3.x = a3.x * scale + x3.x; a3.y = a3.y * scale + x3.y;
            a3.z = a3.z * scale + x3.z; a3.w = a3.w * scale + x3.w;
        }
    }

    const float inv = 1.0f / denom;
    float4* ob = (float4*)(bagbuf + (size_t)bag * CDIM);
    a0.x *= inv; a0.y *= inv; a0.z *= inv; a0.w *= inv;
    a1.x *= inv; a1.y *= inv; a1.z *= inv; a1.w *= inv;
    a2.x *= inv; a2.y *= inv; a2.z *= inv; a2.w *= inv;
    a3.x *= inv; a3.y *= inv; a3.z *= inv; a3.w *= inv;
    ob[lane]       = a0;
    ob[lane + 64]  = a1;
    ob[lane + 128] = a2;
    ob[lane + 192] = a3;
}

// Kernel 2: out[b][r] = sum_c bag[b][c] * W[r][c] + bias[r].
// 16 bags per block, 16 threads per bag, 6-7 r-columns per thread.
// W rows are broadcast across lanes (same address) -> L1/L2 served.
__global__ __launch_bounds__(256) void bag_gemm_kernel(
    const float* __restrict__ bagbuf,
    const float* __restrict__ W,
    const float* __restrict__ bias,
    float* __restrict__ out)
{
    const int t        = threadIdx.x;
    const int localBag = t >> 4;   // 0..15
    const int sub      = t & 15;   // 0..15
    const int bagi     = blockIdx.x * 16 + localBag;
    const int rStart   = (sub < 4) ? sub * 7 : 28 + (sub - 4) * 6;
    const int rCnt     = (sub < 4) ? 7 : 6;

    float acc[7] = {0.f, 0.f, 0.f, 0.f, 0.f, 0.f, 0.f};
    const float4* brow = (const float4*)(bagbuf + (size_t)bagi * CDIM);

    #pragma unroll 2
    for (int kk = 0; kk < CDIM / 4; ++kk) {
        float4 xv = brow[kk];
        #pragma unroll
        for (int j = 0; j < 7; ++j) {
            if (j < rCnt) {
                const float4 wv = *(const float4*)(W + (size_t)(rStart + j) * CDIM + kk * 4);
                acc[j] += dot4(xv, wv);
            }
        }
    }

    #pragma unroll
    for (int j = 0; j < 7; ++j) {
        if (j < rCnt) {
            out[(size_t)bagi * RDIM + rStart + j] = acc[j] + bias[rStart + j];
        }
    }
}

extern "C" void kernel_launch(void* const* d_in, const int* in_sizes, int n_in,
                              void* d_out, int out_size, void* d_ws, size_t ws_size,
                              hipStream_t stream) {
    const float* X    = (const float*)d_in[0];
    const float* Con  = (const float*)d_in[1];
    const float* W    = (const float*)d_in[2];
    const float* bias = (const float*)d_in[3];
    const int* scope  = (const int*)d_in[4];
    const int* rel    = (const int*)d_in[5];
    float* out = (float*)d_out;
    float* bagbuf = (float*)d_ws;   // NBAGS * CDIM * 4 = 33.6 MB

    bag_softmax_kernel<<<NBAGS / 4, 256, 0, stream>>>(X, Con, scope, rel, bagbuf);
    bag_gemm_kernel<<<NBAGS / 16, 256, 0, stream>>>(bagbuf, W, bias, out);
}

// Round 2
// 145.518 us; speedup vs baseline: 3.2543x; 3.2543x over previous
//
#include <hip/hip_runtime.h>
#include <math.h>

#define CDIM 1024
#define RDIM 100
#define NBAGS 8192

typedef float floatx4 __attribute__((ext_vector_type(4)));
typedef short bf16x8 __attribute__((ext_vector_type(8)));

__device__ __forceinline__ float dot4(float4 a, float4 b) {
    return a.x * b.x + a.y * b.y + a.z * b.z + a.w * b.w;
}

// fp32 -> bf16 round-to-nearest-even (values are finite; NaN path not needed)
__device__ __forceinline__ short f2bf(float f) {
    unsigned int u = __builtin_bit_cast(unsigned int, f);
    u += 0x7FFFu + ((u >> 16) & 1u);
    return (short)(u >> 16);
}

// Kernel 1 (UNCHANGED from passing round-1 version): one wave per bag.
// Online softmax with the full 1024-ch accumulator in registers. Reads X once.
__global__ __launch_bounds__(256) void bag_softmax_kernel(
    const float* __restrict__ X,
    const float* __restrict__ Constraints,
    const int* __restrict__ scope,
    const int* __restrict__ rel,
    float* __restrict__ bagbuf)
{
    const int wid  = threadIdx.x >> 6;
    const int lane = threadIdx.x & 63;
    const int bag  = blockIdx.x * 4 + wid;

    const int s = scope[2 * bag];
    const int e = scope[2 * bag + 1];
    const int r = rel[bag];

    const float4* conp = (const float4*)(Constraints + (size_t)r * CDIM);
    const float4 c0 = conp[lane];
    const float4 c1 = conp[lane + 64];
    const float4 c2 = conp[lane + 128];
    const float4 c3 = conp[lane + 192];

    float4 a0 = {0.f, 0.f, 0.f, 0.f};
    float4 a1 = {0.f, 0.f, 0.f, 0.f};
    float4 a2 = {0.f, 0.f, 0.f, 0.f};
    float4 a3 = {0.f, 0.f, 0.f, 0.f};
    float m = -INFINITY;
    float denom = 0.f;

    for (int row = s; row < e; ++row) {
        const float4* xr = (const float4*)(X + (size_t)row * CDIM);
        float4 x0 = xr[lane];
        float4 x1 = xr[lane + 64];
        float4 x2 = xr[lane + 128];
        float4 x3 = xr[lane + 192];

        float p = dot4(x0, c0) + dot4(x1, c1) + dot4(x2, c2) + dot4(x3, c3);
        #pragma unroll
        for (int off = 1; off < 64; off <<= 1)
            p += __shfl_xor(p, off);

        if (p <= m) {
            float w = __expf(p - m);
            denom += w;
            a0.x += w * x0.x; a0.y += w * x0.y; a0.z += w * x0.z; a0.w += w * x0.w;
            a1.x += w * x1.x; a1.y += w * x1.y; a1.z += w * x1.z; a1.w += w * x1.w;
            a2.x += w * x2.x; a2.y += w * x2.y; a2.z += w * x2.z; a2.w += w * x2.w;
            a3.x += w * x3.x; a3.y += w * x3.y; a3.z += w * x3.z; a3.w += w * x3.w;
        } else {
            float scale = __expf(m - p);
            m = p;
            denom = denom * scale + 1.0f;
            a0.x = a0.x * scale + x0.x; a0.y = a0.y * scale + x0.y;
            a0.z = a0.z * scale + x0.z; a0.w = a0.w * scale + x0.w;
            a1.x = a1.x * scale + x1.x; a1.y = a1.y * scale + x1.y;
            a1.z = a1.z * scale + x1.z; a1.w = a1.w * scale + x1.w;
            a2.x = a2.x * scale + x2.x; a2.y = a2.y * scale + x2.y;
            a2.z = a2.z * scale + x2.z; a2.w = a2.w * scale + x2.w;
            a3.x = a3.x * scale + x3.x; a3.y = a3.y * scale + x3.y;
            a3.z = a3.z * scale + x3.z; a3.w = a3.w * scale + x3.w;
        }
    }

    const float inv = 1.0f / denom;
    float4* ob = (float4*)(bagbuf + (size_t)bag * CDIM);
    a0.x *= inv; a0.y *= inv; a0.z *= inv; a0.w *= inv;
    a1.x *= inv; a1.y *= inv; a1.z *= inv; a1.w *= inv;
    a2.x *= inv; a2.y *= inv; a2.z *= inv; a2.w *= inv;
    a3.x *= inv; a3.y *= inv; a3.z *= inv; a3.w *= inv;
    ob[lane]       = a0;
    ob[lane + 64]  = a1;
    ob[lane + 128] = a2;
    ob[lane + 192] = a3;
}

// Kernel 2: MFMA GEMM. out[b][r] = sum_c bag[b][c]*W[r][c] + bias[r].
// One wave per 16 bags; 7 r-tiles of 16 (112 >= 100, masked).
// A-frag: lane&15 = bag row, k = (lane>>4)*8 + i   (fp32 load + RTN cvt)
// B-frag: lane&15 = r col,   k = (lane>>4)*8 + i   (W row-major -> contiguous)
// D:      col = lane&15 (r), row = (lane>>4)*4 + reg (bag)
__global__ __launch_bounds__(128) void bag_gemm_mfma(
    const float* __restrict__ bagbuf,
    const float* __restrict__ W,
    const float* __restrict__ bias,
    float* __restrict__ out)
{
    const int wid  = threadIdx.x >> 6;
    const int lane = threadIdx.x & 63;
    const int bag0 = (blockIdx.x * 2 + wid) * 16;
    const int ln15 = lane & 15;
    const int koff = (lane >> 4) * 8;

    floatx4 acc[7];
    #pragma unroll
    for (int t = 0; t < 7; ++t) acc[t] = (floatx4){0.f, 0.f, 0.f, 0.f};

    const float* aRow = bagbuf + (size_t)(bag0 + ln15) * CDIM + koff;

    for (int kc = 0; kc < CDIM / 32; ++kc) {
        const int k0 = kc * 32;

        float4 af0 = *(const float4*)(aRow + k0);
        float4 af1 = *(const float4*)(aRow + k0 + 4);
        bf16x8 a;
        a[0] = f2bf(af0.x); a[1] = f2bf(af0.y); a[2] = f2bf(af0.z); a[3] = f2bf(af0.w);
        a[4] = f2bf(af1.x); a[5] = f2bf(af1.y); a[6] = f2bf(af1.z); a[7] = f2bf(af1.w);

        #pragma unroll
        for (int t = 0; t < 7; ++t) {
            const int r = t * 16 + ln15;
            bf16x8 b = (bf16x8)0;
            if (r < RDIM) {
                const float* wp = W + (size_t)r * CDIM + k0 + koff;
                float4 w0 = *(const float4*)(wp);
                float4 w1 = *(const float4*)(wp + 4);
                b[0] = f2bf(w0.x); b[1] = f2bf(w0.y); b[2] = f2bf(w0.z); b[3] = f2bf(w0.w);
                b[4] = f2bf(w1.x); b[5] = f2bf(w1.y); b[6] = f2bf(w1.z); b[7] = f2bf(w1.w);
            }
            acc[t] = __builtin_amdgcn_mfma_f32_16x16x32_bf16(a, b, acc[t], 0, 0, 0);
        }
    }

    const int mbase = (lane >> 4) * 4;
    #pragma unroll
    for (int t = 0; t < 7; ++t) {
        const int r = t * 16 + ln15;
        if (r < RDIM) {
            const float bv = bias[r];
            #pragma unroll
            for (int reg = 0; reg < 4; ++reg) {
                const int bag = bag0 + mbase + reg;
                out[(size_t)bag * RDIM + r] = acc[t][reg] + bv;
            }
        }
    }
}

extern "C" void kernel_launch(void* const* d_in, const int* in_sizes, int n_in,
                              void* d_out, int out_size, void* d_ws, size_t ws_size,
                              hipStream_t stream) {
    const float* X    = (const float*)d_in[0];
    const float* Con  = (const float*)d_in[1];
    const float* W    = (const float*)d_in[2];
    const float* bias = (const float*)d_in[3];
    const int* scope  = (const int*)d_in[4];
    const int* rel    = (const int*)d_in[5];
    float* out = (float*)d_out;
    float* bagbuf = (float*)d_ws;   // NBAGS * CDIM * 4 = 33.6 MB

    bag_softmax_kernel<<<NBAGS / 4, 256, 0, stream>>>(X, Con, scope, rel, bagbuf);
    bag_gemm_mfma<<<NBAGS / 32, 128, 0, stream>>>(bagbuf, W, bias, out);
}